// Round 10
// baseline (1058.582 us; speedup 1.0000x reference)
//
#include <hip/hip_runtime.h>
#include <math.h>

#define BB   8
#define CCH  256
#define HH   112
#define HW   12544   // 112*112
#define LDK  40      // fallback conv: padded k-stride in shorts

typedef __attribute__((ext_vector_type(8))) short  bf16x8;
typedef __attribute__((ext_vector_type(4))) short  short4v;
typedef __attribute__((ext_vector_type(4))) float  f32x4;

typedef __attribute__((address_space(1))) const void gm_cv;
typedef __attribute__((address_space(3))) void lds_v;

__device__ __forceinline__ unsigned short f2bf_rne(float f) {
    unsigned u = __float_as_uint(f);
    return (unsigned short)((u + 0x7FFFu + ((u >> 16) & 1u)) >> 16);
}
__device__ __forceinline__ float bf2f(unsigned short h) {
    return __uint_as_float(((unsigned)h) << 16);
}

// ---------------- pre-passes (r8-validated) ----------------

__global__ __launch_bounds__(256) void w_prep(
    const float* __restrict__ w0, const float* __restrict__ w1,
    const float* __restrict__ w2, const float* __restrict__ w3,
    short* __restrict__ dst)
{
    const int which = blockIdx.y;
    const float* src = which == 0 ? w0 : which == 1 ? w1 : which == 2 ? w2 : w3;
    const int base = (blockIdx.x * 256 + threadIdx.x) * 8;
    float4 a = *(const float4*)(src + base);
    float4 b = *(const float4*)(src + base + 4);
    float f[8] = {a.x, a.y, a.z, a.w, b.x, b.y, b.z, b.w};
    bf16x8 h, l;
#pragma unroll
    for (int e = 0; e < 8; ++e) {
        unsigned short hb = f2bf_rne(f[e]);
        h[e] = (short)hb;
        l[e] = (short)f2bf_rne(f[e] - bf2f(hb));
    }
    *(bf16x8*)&dst[(size_t)which * 131072 + base]         = h;
    *(bf16x8*)&dst[(size_t)which * 131072 + 65536 + base] = l;
}

__global__ __launch_bounds__(256) void t_prep(
    const float* __restrict__ src,
    short* __restrict__ dhi, short* __restrict__ dlo)
{
    __shared__ float Ts[32][65];
    const int n0 = blockIdx.x * 64;   // grid.x = 196
    const int c0 = blockIdx.y * 32;   // grid.y = 8
    const int b  = blockIdx.z;
    const int tid = threadIdx.x;
    const int ln  = tid & 63;
    const int wr  = tid >> 6;

#pragma unroll
    for (int i = 0; i < 8; ++i) {
        const int cc = wr * 8 + i;
        Ts[cc][ln] = src[((size_t)b * CCH + c0 + cc) * HW + n0 + ln];
    }
    __syncthreads();

    float f[8];
#pragma unroll
    for (int e = 0; e < 8; ++e) f[e] = Ts[wr * 8 + e][ln];
    bf16x8 h, l;
#pragma unroll
    for (int e = 0; e < 8; ++e) {
        unsigned short hb = f2bf_rne(f[e]);
        h[e] = (short)hb;
        l[e] = (short)f2bf_rne(f[e] - bf2f(hb));
    }
    const size_t o = ((size_t)b * HW + n0 + ln) * CCH + c0 + wr * 8;
    *(bf16x8*)&dhi[o] = h;
    *(bf16x8*)&dlo[o] = l;
}

// ---------------- conv v4: B-resident-in-LDS, A-direct, multi-m-tile -------
// Block owns 128 pixels; stages B (full K=256, hi/lo, 128 KiB) ONCE into LDS
// in two K-halves (compute on half 1 overlaps half 2's loads), then computes
// all m-tiles of one or two weight sets (KV fused) streaming A from L2.
// No per-K-step barriers: B is read-only after staging.
// LDS layout per plane: [kh][row][16 slots of 16B], slot ^= row&7 swizzle.
__global__ __launch_bounds__(256) void conv_v4(
    const short* __restrict__ W0hi, const short* __restrict__ W0lo,
    const short* __restrict__ W1hi, const short* __restrict__ W1lo,
    const short* __restrict__ Xthi, const short* __restrict__ Xtlo,
    float* __restrict__ Y0, float* __restrict__ Y1,
    const float* __restrict__ Res)
{
    const int blk = blockIdx.x;            // 0..783
    const int b    = blk / 98;
    const int pix0 = (blk % 98) * 128;

    const int tid = threadIdx.x;
    const int lane = tid & 63, wid = tid >> 6;
    const int wr = wid >> 1, wc = wid & 1;
    const int fr = lane & 15, fg = lane >> 4;

    __shared__ __align__(16) short Bsh[2][128 * 128];  // [khalf][row*128+col]
    __shared__ __align__(16) short Bsl[2][128 * 128];

    const size_t xbase = (size_t)(blk * 128) * CCH;    // flat (b*HW+pix)*256

    // stage one K-half: 32 chunks of 1KB per plane, wave stages 8 chunks
    auto STAGEH = [&](int kh) {
#pragma unroll
        for (int it = 0; it < 8; ++it) {
            const int c  = wid * 8 + it;            // chunk 0..31
            const int rl = c * 4 + (lane >> 4);     // row 0..127
            const int sl = lane & 15;               // phys slot
            const int scol = kh * 128 + ((sl ^ (rl & 7)) << 3);
            const size_t xo = xbase + (size_t)rl * CCH + scol;
            __builtin_amdgcn_global_load_lds((gm_cv*)(Xthi + xo), (lds_v*)&Bsh[kh][c * 512], 16, 0, 0);
            __builtin_amdgcn_global_load_lds((gm_cv*)(Xtlo + xo), (lds_v*)&Bsl[kh][c * 512], 16, 0, 0);
        }
    };

    STAGEH(0);
    STAGEH(1);
    asm volatile("s_waitcnt vmcnt(16)" ::: "memory");   // half 1 landed
    __builtin_amdgcn_s_barrier();

    bool h2_waited = false;
#pragma unroll 1
    for (int set = 0; set < 2; ++set) {
        const short* Ahi = set ? W1hi : W0hi;
        const short* Alo = set ? W1lo : W0lo;
        float*       Yo  = set ? Y1   : Y0;
        if (!Ahi) break;

#pragma unroll 1
        for (int mt = 0; mt < 2; ++mt) {
            f32x4 acc[4][4];
#pragma unroll
            for (int m = 0; m < 4; ++m)
#pragma unroll
                for (int nf = 0; nf < 4; ++nf) acc[m][nf] = (f32x4){0.f, 0.f, 0.f, 0.f};

            const size_t abase = (size_t)(mt * 128 + wr * 64 + fr) * CCH + fg * 8;

#pragma unroll
            for (int t = 0; t < 8; ++t) {
                if (t == 4 && !h2_waited) {
                    asm volatile("s_waitcnt vmcnt(0)" ::: "memory");
                    __builtin_amdgcn_s_barrier();
                    h2_waited = true;
                }
                const int kh = t >> 2, lt = t & 3;

                bf16x8 ah[4], al[4];
#pragma unroll
                for (int m = 0; m < 4; ++m) {
                    ah[m] = *(const bf16x8*)(Ahi + abase + (size_t)m * 16 * CCH + t * 32);
                    al[m] = *(const bf16x8*)(Alo + abase + (size_t)m * 16 * CCH + t * 32);
                }
                bf16x8 bh[4], bl[4];
#pragma unroll
                for (int nf = 0; nf < 4; ++nf) {
                    const int row = wc * 64 + nf * 16 + fr;
                    const int off = row * 128 + (((lt * 4 + fg) ^ (row & 7)) << 3);
                    bh[nf] = *(const bf16x8*)&Bsh[kh][off];
                    bl[nf] = *(const bf16x8*)&Bsl[kh][off];
                }
#pragma unroll
                for (int m = 0; m < 4; ++m)
#pragma unroll
                    for (int nf = 0; nf < 4; ++nf) {
                        acc[m][nf] = __builtin_amdgcn_mfma_f32_16x16x32_bf16(ah[m], bh[nf], acc[m][nf], 0, 0, 0);
                        acc[m][nf] = __builtin_amdgcn_mfma_f32_16x16x32_bf16(ah[m], bl[nf], acc[m][nf], 0, 0, 0);
                        acc[m][nf] = __builtin_amdgcn_mfma_f32_16x16x32_bf16(al[m], bh[nf], acc[m][nf], 0, 0, 0);
                    }
            }

            // epilogue (C/D layout HW-verified r5)
#pragma unroll
            for (int m = 0; m < 4; ++m)
#pragma unroll
                for (int nf = 0; nf < 4; ++nf) {
                    const int gcol = pix0 + wc * 64 + nf * 16 + fr;
#pragma unroll
                    for (int q = 0; q < 4; ++q) {
                        const int grow = mt * 128 + wr * 64 + m * 16 + fg * 4 + q;
                        const size_t idx = ((size_t)b * CCH + grow) * HW + gcol;
                        float v = acc[m][nf][q];
                        if (Res) v = fmaxf(v + Res[idx], 0.f);
                        Yo[idx] = v;
                    }
                }
        }
    }
}

// ---------------- MFMA attention v2 (r9-validated) ----------------
__global__ __launch_bounds__(512) void attn_mfma2(
    const float* __restrict__ Qg,
    const float* __restrict__ Kg,
    const float* __restrict__ Vg,
    float* __restrict__ Zg)
{
    const int bc   = blockIdx.x;
    const int tid  = threadIdx.x;
    const int lane = tid & 63;
    const int wid  = tid >> 6;
    const int t    = lane & 15;
    const int g    = lane >> 4;

    __shared__ __align__(16) short KTh[112 * 128];
    __shared__ __align__(16) short KTl[112 * 128];
    __shared__ __align__(16) short VTh[112 * 128];
    __shared__ __align__(16) short VTl[112 * 128];

    for (int i = tid; i < 3584; i += 512) {
        *(short4v*)&KTh[i * 4] = (short4v){0, 0, 0, 0};
        *(short4v*)&KTl[i * 4] = (short4v){0, 0, 0, 0};
        *(short4v*)&VTh[i * 4] = (short4v){0, 0, 0, 0};
        *(short4v*)&VTl[i * 4] = (short4v){0, 0, 0, 0};
    }
    __syncthreads();

    const float* Qp = Qg + (size_t)bc * HW;
    const float* Kp = Kg + (size_t)bc * HW;
    const float* Vp = Vg + (size_t)bc * HW;

    for (int it = tid; it < 14 * 112; it += 512) {
        const int ko = it / 112;
        const int j  = it - ko * 112;
        bf16x8 h, l;
#pragma unroll
        for (int r = 0; r < 8; ++r) {
            const float v = Kp[(ko * 8 + r) * 112 + j];
            const unsigned short hb = f2bf_rne(v);
            h[r] = (short)hb;
            l[r] = (short)f2bf_rne(v - bf2f(hb));
        }
        const int col = ((ko ^ (j & 7)) << 3);
        *(bf16x8*)&KTh[j * 128 + col] = h;
        *(bf16x8*)&KTl[j * 128 + col] = l;
    }
    for (int it = tid; it < 14 * 112; it += 512) {
        const int jo = it / 112;
        const int w  = it - jo * 112;
        bf16x8 h, l;
#pragma unroll
        for (int r = 0; r < 8; ++r) {
            const float v = Vp[(jo * 8 + r) * 112 + w];
            const unsigned short hb = f2bf_rne(v);
            h[r] = (short)hb;
            l[r] = (short)f2bf_rne(v - bf2f(hb));
        }
        const int col = ((jo ^ (w & 7)) << 3);
        *(bf16x8*)&VTh[w * 128 + col] = h;
        *(bf16x8*)&VTl[w * 128 + col] = l;
    }

    bf16x8 qh[4], ql[4];
    if (wid < 7) {
        const float* qrow = Qp + (size_t)(16 * wid + t) * 112;
#pragma unroll
        for (int s = 0; s < 4; ++s) {
            const int k0 = 32 * s + 8 * g;
            if (k0 < 112) {
                float4 a = *(const float4*)(qrow + k0);
                float4 b = *(const float4*)(qrow + k0 + 4);
                float f[8] = {a.x, a.y, a.z, a.w, b.x, b.y, b.z, b.w};
#pragma unroll
                for (int e = 0; e < 8; ++e) {
                    unsigned short hb = f2bf_rne(f[e]);
                    qh[s][e] = (short)hb;
                    ql[s][e] = (short)f2bf_rne(f[e] - bf2f(hb));
                }
            } else {
#pragma unroll
                for (int e = 0; e < 8; ++e) { qh[s][e] = 0; ql[s][e] = 0; }
            }
        }
    }
    __syncthreads();

    f32x4 acc[7];
#pragma unroll
    for (int fj = 0; fj < 7; ++fj) acc[fj] = (f32x4){0.f, 0.f, 0.f, 0.f};

    if (wid < 7) {
#pragma unroll
        for (int s = 0; s < 4; ++s)
#pragma unroll
            for (int fj = 0; fj < 7; ++fj) {
                const int jr  = 16 * fj + t;
                const int off = jr * 128 + (((4 * s + g) ^ (jr & 7)) << 3);
                bf16x8 kh = *(const bf16x8*)&KTh[off];
                bf16x8 kl = *(const bf16x8*)&KTl[off];
                acc[fj] = __builtin_amdgcn_mfma_f32_16x16x32_bf16(qh[s], kh, acc[fj], 0, 0, 0);
                acc[fj] = __builtin_amdgcn_mfma_f32_16x16x32_bf16(qh[s], kl, acc[fj], 0, 0, 0);
                acc[fj] = __builtin_amdgcn_mfma_f32_16x16x32_bf16(ql[s], kh, acc[fj], 0, 0, 0);
            }

        float mx[4], sm[4];
#pragma unroll
        for (int q = 0; q < 4; ++q) {
            mx[q] = acc[0][q];
#pragma unroll
            for (int fj = 1; fj < 7; ++fj) mx[q] = fmaxf(mx[q], acc[fj][q]);
#pragma unroll
            for (int off = 1; off < 16; off <<= 1) mx[q] = fmaxf(mx[q], __shfl_xor(mx[q], off));
            sm[q] = 0.f;
        }
#pragma unroll
        for (int fj = 0; fj < 7; ++fj)
#pragma unroll
            for (int q = 0; q < 4; ++q) {
                float e = __expf(acc[fj][q] - mx[q]);
                acc[fj][q] = e;
                sm[q] += e;
            }
#pragma unroll
        for (int q = 0; q < 4; ++q) {
#pragma unroll
            for (int off = 1; off < 16; off <<= 1) sm[q] += __shfl_xor(sm[q], off);
            sm[q] = 1.0f / sm[q];
        }
#pragma unroll
        for (int fj = 0; fj < 7; ++fj)
#pragma unroll
            for (int q = 0; q < 4; ++q) acc[fj][q] *= sm[q];
    }

    __syncthreads();

    if (wid < 7) {
#pragma unroll
        for (int fj = 0; fj < 7; ++fj)
#pragma unroll
            for (int q = 0; q < 4; ++q) {
                const float v = acc[fj][q];
                const int i = 16 * wid + 4 * g + q;
                const int j = 16 * fj + t;
                const int col = (((j >> 3) ^ (i & 7)) << 3) | (j & 7);
                const unsigned short hb = f2bf_rne(v);
                KTh[i * 128 + col] = (short)hb;
                KTl[i * 128 + col] = (short)f2bf_rne(v - bf2f(hb));
            }

        f32x4 zc[7];
#pragma unroll
        for (int fw = 0; fw < 7; ++fw) zc[fw] = (f32x4){0.f, 0.f, 0.f, 0.f};
#pragma unroll
        for (int s = 0; s < 4; ++s) {
            const int ir   = 16 * wid + t;
            const int offm = ir * 128 + (((4 * s + g) ^ (ir & 7)) << 3);
            bf16x8 mh = *(const bf16x8*)&KTh[offm];
            bf16x8 ml = *(const bf16x8*)&KTl[offm];
#pragma unroll
            for (int fw = 0; fw < 7; ++fw) {
                const int vr  = 16 * fw + t;
                const int off = vr * 128 + (((4 * s + g) ^ (vr & 7)) << 3);
                bf16x8 bh = *(const bf16x8*)&VTh[off];
                bf16x8 bl = *(const bf16x8*)&VTl[off];
                zc[fw] = __builtin_amdgcn_mfma_f32_16x16x32_bf16(mh, bh, zc[fw], 0, 0, 0);
                zc[fw] = __builtin_amdgcn_mfma_f32_16x16x32_bf16(mh, bl, zc[fw], 0, 0, 0);
                zc[fw] = __builtin_amdgcn_mfma_f32_16x16x32_bf16(ml, bh, zc[fw], 0, 0, 0);
            }
        }

        float* Zp = Zg + (size_t)bc * HW;
#pragma unroll
        for (int fw = 0; fw < 7; ++fw)
#pragma unroll
            for (int q = 0; q < 4; ++q)
                Zp[(size_t)(16 * wid + 4 * g + q) * 112 + 16 * fw + t] = zc[fw][q];
    }
}

// ---------------- fallback path (r5-proven) ----------------
__global__ __launch_bounds__(256) void conv_mfma(
    const float* __restrict__ Wm,
    const float* __restrict__ Xin,
    float* __restrict__ Yout,
    const float* __restrict__ Res)
{
    const int bn  = blockIdx.x;
    const int bm  = blockIdx.y;
    const int b   = blockIdx.z;
    const int tid = threadIdx.x;

    __shared__ __align__(16) short As[2][128 * LDK];
    __shared__ __align__(16) short Bs[2][128 * LDK];

    const float* Xb = Xin + (size_t)b * CCH * HW;

    f32x4 acc[4][4];
#pragma unroll
    for (int m = 0; m < 4; ++m)
#pragma unroll
        for (int nf = 0; nf < 4; ++nf) acc[m][nf] = (f32x4){0.f, 0.f, 0.f, 0.f};

    const int ao  = tid >> 1;
    const int akh = (tid & 1) << 4;
    const int bnp = tid & 31;
    const int bcp = tid >> 5;

    const int lane = tid & 63;
    const int wid  = tid >> 6;
    const int wr = wid >> 1, wc = wid & 1;
    const int fr = lane & 15;
    const int fg = lane >> 4;

    for (int k0 = 0; k0 < CCH; k0 += 32) {
        {
            const float* wsrc = Wm + (size_t)(bm * 128 + ao) * CCH + k0 + akh;
            float4 w0 = *(const float4*)(wsrc + 0);
            float4 w1 = *(const float4*)(wsrc + 4);
            float4 w2 = *(const float4*)(wsrc + 8);
            float4 w3 = *(const float4*)(wsrc + 12);
            float wf[16] = {w0.x, w0.y, w0.z, w0.w, w1.x, w1.y, w1.z, w1.w,
                            w2.x, w2.y, w2.z, w2.w, w3.x, w3.y, w3.z, w3.w};
            bf16x8 h0, h1, l0, l1;
#pragma unroll
            for (int i = 0; i < 8; ++i) {
                unsigned short hb = f2bf_rne(wf[i]);
                h0[i] = (short)hb;
                l0[i] = (short)f2bf_rne(wf[i] - bf2f(hb));
            }
#pragma unroll
            for (int i = 0; i < 8; ++i) {
                unsigned short hb = f2bf_rne(wf[8 + i]);
                h1[i] = (short)hb;
                l1[i] = (short)f2bf_rne(wf[8 + i] - bf2f(hb));
            }
            *(bf16x8*)&As[0][ao * LDK + akh]     = h0;
            *(bf16x8*)&As[0][ao * LDK + akh + 8] = h1;
            *(bf16x8*)&As[1][ao * LDK + akh]     = l0;
            *(bf16x8*)&As[1][ao * LDK + akh + 8] = l1;
        }
        {
            const float* xsrc = Xb + (size_t)(k0 + bcp * 4) * HW + (size_t)bn * 128 + bnp * 4;
            float4 r0 = *(const float4*)(xsrc);
            float4 r1 = *(const float4*)(xsrc + HW);
            float4 r2 = *(const float4*)(xsrc + 2 * HW);
            float4 r3 = *(const float4*)(xsrc + 3 * HW);
            float rf[4][4] = {{r0.x, r0.y, r0.z, r0.w},
                              {r1.x, r1.y, r1.z, r1.w},
                              {r2.x, r2.y, r2.z, r2.w},
                              {r3.x, r3.y, r3.z, r3.w}};
#pragma unroll
            for (int j = 0; j < 4; ++j) {
                short4v hv, lv;
#pragma unroll
                for (int rr = 0; rr < 4; ++rr) {
                    unsigned short hb = f2bf_rne(rf[rr][j]);
                    hv[rr] = (short)hb;
                    lv[rr] = (short)f2bf_rne(rf[rr][j] - bf2f(hb));
                }
                *(short4v*)&Bs[0][(bnp * 4 + j) * LDK + bcp * 4] = hv;
                *(short4v*)&Bs[1][(bnp * 4 + j) * LDK + bcp * 4] = lv;
            }
        }
        __syncthreads();

        bf16x8 ah[4], al[4], bh[4], bl[4];
#pragma unroll
        for (int m = 0; m < 4; ++m) {
            const int off = (wr * 64 + m * 16 + fr) * LDK + fg * 8;
            ah[m] = *(const bf16x8*)&As[0][off];
            al[m] = *(const bf16x8*)&As[1][off];
        }
#pragma unroll
        for (int nf = 0; nf < 4; ++nf) {
            const int off = (wc * 64 + nf * 16 + fr) * LDK + fg * 8;
            bh[nf] = *(const bf16x8*)&Bs[0][off];
            bl[nf] = *(const bf16x8*)&Bs[1][off];
        }
#pragma unroll
        for (int m = 0; m < 4; ++m)
#pragma unroll
            for (int nf = 0; nf < 4; ++nf) {
                acc[m][nf] = __builtin_amdgcn_mfma_f32_16x16x32_bf16(ah[m], bh[nf], acc[m][nf], 0, 0, 0);
                acc[m][nf] = __builtin_amdgcn_mfma_f32_16x16x32_bf16(ah[m], bl[nf], acc[m][nf], 0, 0, 0);
                acc[m][nf] = __builtin_amdgcn_mfma_f32_16x16x32_bf16(al[m], bh[nf], acc[m][nf], 0, 0, 0);
            }
        __syncthreads();
    }

#pragma unroll
    for (int m = 0; m < 4; ++m)
#pragma unroll
        for (int nf = 0; nf < 4; ++nf) {
            const int gcol = bn * 128 + wc * 64 + nf * 16 + fr;
#pragma unroll
            for (int q = 0; q < 4; ++q) {
                const int grow = bm * 128 + wr * 64 + m * 16 + fg * 4 + q;
                const size_t idx = ((size_t)b * CCH + grow) * HW + gcol;
                float v = acc[m][nf][q];
                if (Res) v = fmaxf(v + Res[idx], 0.f);
                Yout[idx] = v;
            }
        }
}

__global__ __launch_bounds__(512) void attn_valu(
    const float* __restrict__ Qg,
    const float* __restrict__ Kg,
    const float* __restrict__ Vg,
    float* __restrict__ Zg)
{
    const int bc  = blockIdx.x;
    const int tid = threadIdx.x;
    const int tx  = tid & 15;
    const int ty  = tid >> 4;

    __shared__ float Qs[HH][116];
    __shared__ float Ks[HH][116];
    __shared__ float Vs[HH][116];

    const float* Qp = Qg + (size_t)bc * HW;
    const float* Kp = Kg + (size_t)bc * HW;
    const float* Vp = Vg + (size_t)bc * HW;

    for (int idx = tid; idx < HW / 4; idx += 512) {
        int row = idx / 28;
        int c4  = (idx % 28) * 4;
        *(float4*)&Qs[row][c4] = *(const float4*)(Qp + row * HH + c4);
        *(float4*)&Ks[row][c4] = *(const float4*)(Kp + row * HH + c4);
        *(float4*)&Vs[row][c4] = *(const float4*)(Vp + row * HH + c4);
    }
    __syncthreads();

    const bool act = (ty < 28);
    const int i0 = ty * 4;
    const int j0 = tx * 7;

    float s[4][7];
    if (act) {
#pragma unroll
        for (int ii = 0; ii < 4; ++ii)
#pragma unroll
            for (int jj = 0; jj < 7; ++jj) s[ii][jj] = 0.f;
        for (int k = 0; k < HH; ++k) {
            float qv[4], kv[7];
#pragma unroll
            for (int ii = 0; ii < 4; ++ii) qv[ii] = Qs[i0 + ii][k];
#pragma unroll
            for (int jj = 0; jj < 7; ++jj) kv[jj] = Ks[k][j0 + jj];
#pragma unroll
            for (int ii = 0; ii < 4; ++ii)
#pragma unroll
                for (int jj = 0; jj < 7; ++jj)
                    s[ii][jj] = fmaf(qv[ii], kv[jj], s[ii][jj]);
        }
#pragma unroll
        for (int ii = 0; ii < 4; ++ii) {
            float mx = s[ii][0];
#pragma unroll
            for (int jj = 1; jj < 7; ++jj) mx = fmaxf(mx, s[ii][jj]);
#pragma unroll
            for (int off = 1; off < 16; off <<= 1) mx = fmaxf(mx, __shfl_xor(mx, off));
            float sum = 0.f;
#pragma unroll
            for (int jj = 0; jj < 7; ++jj) {
                float e = __expf(s[ii][jj] - mx);
                s[ii][jj] = e;
                sum += e;
            }
#pragma unroll
            for (int off = 1; off < 16; off <<= 1) sum += __shfl_xor(sum, off);
            float inv = 1.0f / sum;
#pragma unroll
            for (int jj = 0; jj < 7; ++jj) s[ii][jj] *= inv;
        }
    }

    __syncthreads();
    if (act) {
#pragma unroll
        for (int ii = 0; ii < 4; ++ii)
#pragma unroll
            for (int jj = 0; jj < 7; ++jj)
                Qs[i0 + ii][j0 + jj] = s[ii][jj];
    }
    __syncthreads();

    if (act) {
        float z[4][7];
#pragma unroll
        for (int ii = 0; ii < 4; ++ii)
#pragma unroll
            for (int ww = 0; ww < 7; ++ww) z[ii][ww] = 0.f;
        for (int j = 0; j < HH; ++j) {
            float mv[4], vv[7];
#pragma unroll
            for (int ii = 0; ii < 4; ++ii) mv[ii] = Qs[i0 + ii][j];
#pragma unroll
            for (int ww = 0; ww < 7; ++ww) vv[ww] = Vs[j][j0 + ww];
#pragma unroll
            for (int ii = 0; ii < 4; ++ii)
#pragma unroll
                for (int ww = 0; ww < 7; ++ww)
                    z[ii][ww] = fmaf(mv[ii], vv[ww], z[ii][ww]);
        }
        float* Zp = Zg + (size_t)bc * HW;
#pragma unroll
        for (int ii = 0; ii < 4; ++ii)
#pragma unroll
            for (int ww = 0; ww < 7; ++ww)
                Zp[(i0 + ii) * HH + j0 + ww] = z[ii][ww];
    }
}

extern "C" void kernel_launch(void* const* d_in, const int* in_sizes, int n_in,
                              void* d_out, int out_size, void* d_ws, size_t ws_size,
                              hipStream_t stream) {
    const float* x  = (const float*)d_in[0];
    const float* y  = (const float*)d_in[1];
    const float* WQ = (const float*)d_in[2];
    const float* WK = (const float*)d_in[3];
    const float* WV = (const float*)d_in[4];
    const float* WZ = (const float*)d_in[5];
    float* out = (float*)d_out;

    const size_t n = (size_t)BB * CCH * HW;
    const size_t S_BYTES = n * 4;
    const size_t NEED = 3 * S_BYTES + (size_t)4 * CCH * CCH * 2 * sizeof(short);

    if (ws_size >= NEED) {
        short* At_hi = (short*)d_ws;
        short* At_lo = At_hi + n;
        float* Kb = (float*)((char*)d_ws + S_BYTES);
        float* Vb = (float*)((char*)d_ws + 2 * S_BYTES);
        short* Wb = (short*)((char*)d_ws + 3 * S_BYTES);
        float* Qb = out;
        float* Zb = Kb;

        dim3 tgrid(HW / 64, CCH / 32, BB);
        dim3 cgrid(784);

        w_prep<<<dim3(32, 4), 256, 0, stream>>>(WQ, WK, WV, WZ, Wb);
        t_prep<<<tgrid, 256, 0, stream>>>(x, At_hi, At_lo);
        conv_v4<<<cgrid, 256, 0, stream>>>(Wb, Wb + 65536, nullptr, nullptr,
                                           At_hi, At_lo, Qb, nullptr, nullptr);
        t_prep<<<tgrid, 256, 0, stream>>>(y, At_hi, At_lo);
        conv_v4<<<cgrid, 256, 0, stream>>>(Wb + 131072, Wb + 131072 + 65536,
                                           Wb + 262144, Wb + 262144 + 65536,
                                           At_hi, At_lo, Kb, Vb, nullptr);
        attn_mfma2<<<dim3(2048), 512, 0, stream>>>(Qb, Kb, Vb, Zb);
        t_prep<<<tgrid, 256, 0, stream>>>(Zb, At_hi, At_lo);
        conv_v4<<<cgrid, 256, 0, stream>>>(Wb + 393216, Wb + 393216 + 65536, nullptr, nullptr,
                                           At_hi, At_lo, out, nullptr, x);
    } else {
        float* Kb = (float*)d_ws;
        float* Vb = Kb + n;
        float* Zb = Kb;
        float* Qb = out;
        dim3 grid(98, 2, 8);
        conv_mfma<<<grid, 256, 0, stream>>>(WQ, x, Qb, nullptr);
        conv_mfma<<<grid, 256, 0, stream>>>(WK, y, Kb, nullptr);
        conv_mfma<<<grid, 256, 0, stream>>>(WV, y, Vb, nullptr);
        attn_valu<<<dim3(2048), 512, 0, stream>>>(Qb, Kb, Vb, Zb);
        conv_mfma<<<grid, 256, 0, stream>>>(WZ, Zb, out, x);
    }
}

// Round 11
// 641.377 us; speedup vs baseline: 1.6505x; 1.6505x over previous
//
#include <hip/hip_runtime.h>
#include <math.h>

#define BB   8
#define CCH  256
#define HH   112
#define HW   12544   // 112*112
#define LDK  40      // conv: padded k-stride in shorts (32+8)

typedef __attribute__((ext_vector_type(8))) short  bf16x8;
typedef __attribute__((ext_vector_type(4))) short  short4v;
typedef __attribute__((ext_vector_type(4))) float  f32x4;

__device__ __forceinline__ unsigned short f2bf_rne(float f) {
    unsigned u = __float_as_uint(f);
    return (unsigned short)((u + 0x7FFFu + ((u >> 16) & 1u)) >> 16);
}
__device__ __forceinline__ float bf2f(unsigned short h) {
    return __uint_as_float(((unsigned)h) << 16);
}

// ---------------- conv (r5-proven, ~129us/dispatch): in-kernel conversion,
// split-bf16 3-term MFMA, 128x128 tile, BK=32, 40KB LDS ----------------
__global__ __launch_bounds__(256) void conv_mfma(
    const float* __restrict__ Wm,
    const float* __restrict__ Xin,
    float* __restrict__ Yout,
    const float* __restrict__ Res)
{
    const int bn  = blockIdx.x;
    const int bm  = blockIdx.y;
    const int b   = blockIdx.z;
    const int tid = threadIdx.x;

    __shared__ __align__(16) short As[2][128 * LDK];
    __shared__ __align__(16) short Bs[2][128 * LDK];

    const float* Xb = Xin + (size_t)b * CCH * HW;

    f32x4 acc[4][4];
#pragma unroll
    for (int m = 0; m < 4; ++m)
#pragma unroll
        for (int nf = 0; nf < 4; ++nf) acc[m][nf] = (f32x4){0.f, 0.f, 0.f, 0.f};

    const int ao  = tid >> 1;
    const int akh = (tid & 1) << 4;
    const int bnp = tid & 31;
    const int bcp = tid >> 5;

    const int lane = tid & 63;
    const int wid  = tid >> 6;
    const int wr = wid >> 1, wc = wid & 1;
    const int fr = lane & 15;
    const int fg = lane >> 4;

    for (int k0 = 0; k0 < CCH; k0 += 32) {
        {
            const float* wsrc = Wm + (size_t)(bm * 128 + ao) * CCH + k0 + akh;
            float4 w0 = *(const float4*)(wsrc + 0);
            float4 w1 = *(const float4*)(wsrc + 4);
            float4 w2 = *(const float4*)(wsrc + 8);
            float4 w3 = *(const float4*)(wsrc + 12);
            float wf[16] = {w0.x, w0.y, w0.z, w0.w, w1.x, w1.y, w1.z, w1.w,
                            w2.x, w2.y, w2.z, w2.w, w3.x, w3.y, w3.z, w3.w};
            bf16x8 h0, h1, l0, l1;
#pragma unroll
            for (int i = 0; i < 8; ++i) {
                unsigned short hb = f2bf_rne(wf[i]);
                h0[i] = (short)hb;
                l0[i] = (short)f2bf_rne(wf[i] - bf2f(hb));
            }
#pragma unroll
            for (int i = 0; i < 8; ++i) {
                unsigned short hb = f2bf_rne(wf[8 + i]);
                h1[i] = (short)hb;
                l1[i] = (short)f2bf_rne(wf[8 + i] - bf2f(hb));
            }
            *(bf16x8*)&As[0][ao * LDK + akh]     = h0;
            *(bf16x8*)&As[0][ao * LDK + akh + 8] = h1;
            *(bf16x8*)&As[1][ao * LDK + akh]     = l0;
            *(bf16x8*)&As[1][ao * LDK + akh + 8] = l1;
        }
        {
            const float* xsrc = Xb + (size_t)(k0 + bcp * 4) * HW + (size_t)bn * 128 + bnp * 4;
            float4 r0 = *(const float4*)(xsrc);
            float4 r1 = *(const float4*)(xsrc + HW);
            float4 r2 = *(const float4*)(xsrc + 2 * HW);
            float4 r3 = *(const float4*)(xsrc + 3 * HW);
            float rf[4][4] = {{r0.x, r0.y, r0.z, r0.w},
                              {r1.x, r1.y, r1.z, r1.w},
                              {r2.x, r2.y, r2.z, r2.w},
                              {r3.x, r3.y, r3.z, r3.w}};
#pragma unroll
            for (int j = 0; j < 4; ++j) {
                short4v hv, lv;
#pragma unroll
                for (int rr = 0; rr < 4; ++rr) {
                    unsigned short hb = f2bf_rne(rf[rr][j]);
                    hv[rr] = (short)hb;
                    lv[rr] = (short)f2bf_rne(rf[rr][j] - bf2f(hb));
                }
                *(short4v*)&Bs[0][(bnp * 4 + j) * LDK + bcp * 4] = hv;
                *(short4v*)&Bs[1][(bnp * 4 + j) * LDK + bcp * 4] = lv;
            }
        }
        __syncthreads();

        bf16x8 ah[4], al[4], bh[4], bl[4];
#pragma unroll
        for (int m = 0; m < 4; ++m) {
            const int off = (wr * 64 + m * 16 + fr) * LDK + fg * 8;
            ah[m] = *(const bf16x8*)&As[0][off];
            al[m] = *(const bf16x8*)&As[1][off];
        }
#pragma unroll
        for (int nf = 0; nf < 4; ++nf) {
            const int off = (wc * 64 + nf * 16 + fr) * LDK + fg * 8;
            bh[nf] = *(const bf16x8*)&Bs[0][off];
            bl[nf] = *(const bf16x8*)&Bs[1][off];
        }
#pragma unroll
        for (int m = 0; m < 4; ++m)
#pragma unroll
            for (int nf = 0; nf < 4; ++nf) {
                acc[m][nf] = __builtin_amdgcn_mfma_f32_16x16x32_bf16(ah[m], bh[nf], acc[m][nf], 0, 0, 0);
                acc[m][nf] = __builtin_amdgcn_mfma_f32_16x16x32_bf16(ah[m], bl[nf], acc[m][nf], 0, 0, 0);
                acc[m][nf] = __builtin_amdgcn_mfma_f32_16x16x32_bf16(al[m], bh[nf], acc[m][nf], 0, 0, 0);
            }
        __syncthreads();
    }

#pragma unroll
    for (int m = 0; m < 4; ++m)
#pragma unroll
        for (int nf = 0; nf < 4; ++nf) {
            const int gcol = bn * 128 + wc * 64 + nf * 16 + fr;
#pragma unroll
            for (int q = 0; q < 4; ++q) {
                const int grow = bm * 128 + wr * 64 + m * 16 + fg * 4 + q;
                const size_t idx = ((size_t)b * CCH + grow) * HW + gcol;
                float v = acc[m][nf][q];
                if (Res) v = fmaxf(v + Res[idx], 0.f);
                Yout[idx] = v;
            }
        }
}

// ---------------- MFMA attention, pure bf16 (tolerance probe) ----------------
// attn_mfma2 structure (r9-validated layouts/swizzles) with all lo planes and
// lo MFMA terms removed: LDS 112KB->56KB (2 blocks/CU), 1/3 the MFMAs.
__global__ __launch_bounds__(512) void attn_bf16(
    const float* __restrict__ Qg,
    const float* __restrict__ Kg,
    const float* __restrict__ Vg,
    float* __restrict__ Zg)
{
    const int bc   = blockIdx.x;
    const int tid  = threadIdx.x;
    const int lane = tid & 63;
    const int wid  = tid >> 6;
    const int t    = lane & 15;
    const int g    = lane >> 4;

    __shared__ __align__(16) short KTh[112 * 128];   // reused for M
    __shared__ __align__(16) short VTh[112 * 128];

    // zero-init (k/j >= 112 padding)
    for (int i = tid; i < 3584; i += 512) {
        *(short4v*)&KTh[i * 4] = (short4v){0, 0, 0, 0};
        *(short4v*)&VTh[i * 4] = (short4v){0, 0, 0, 0};
    }
    __syncthreads();

    const float* Qp = Qg + (size_t)bc * HW;
    const float* Kp = Kg + (size_t)bc * HW;
    const float* Vp = Vg + (size_t)bc * HW;

    // K^T: lane (ko,j) reads K[8ko..8ko+7][j] -> KT[j][swz(ko)] one b128 write
    for (int it = tid; it < 14 * 112; it += 512) {
        const int ko = it / 112;
        const int j  = it - ko * 112;
        bf16x8 h;
#pragma unroll
        for (int r = 0; r < 8; ++r)
            h[r] = (short)f2bf_rne(Kp[(ko * 8 + r) * 112 + j]);
        *(bf16x8*)&KTh[j * 128 + ((ko ^ (j & 7)) << 3)] = h;
    }
    // V^T: lane (jo,w) reads V[8jo..8jo+7][w] -> VT[w][swz(jo)]
    for (int it = tid; it < 14 * 112; it += 512) {
        const int jo = it / 112;
        const int w  = it - jo * 112;
        bf16x8 h;
#pragma unroll
        for (int r = 0; r < 8; ++r)
            h[r] = (short)f2bf_rne(Vp[(jo * 8 + r) * 112 + w]);
        *(bf16x8*)&VTh[w * 128 + ((jo ^ (w & 7)) << 3)] = h;
    }

    // Q fragments (rows i = 16*wid + t), k>=112 zero
    bf16x8 qh[4];
    if (wid < 7) {
        const float* qrow = Qp + (size_t)(16 * wid + t) * 112;
#pragma unroll
        for (int s = 0; s < 4; ++s) {
            const int k0 = 32 * s + 8 * g;
            if (k0 < 112) {
                float4 a = *(const float4*)(qrow + k0);
                float4 b = *(const float4*)(qrow + k0 + 4);
                float f[8] = {a.x, a.y, a.z, a.w, b.x, b.y, b.z, b.w};
#pragma unroll
                for (int e = 0; e < 8; ++e) qh[s][e] = (short)f2bf_rne(f[e]);
            } else {
#pragma unroll
                for (int e = 0; e < 8; ++e) qh[s][e] = 0;
            }
        }
    }
    __syncthreads();

    // ---- QK^T ----
    f32x4 acc[7];
#pragma unroll
    for (int fj = 0; fj < 7; ++fj) acc[fj] = (f32x4){0.f, 0.f, 0.f, 0.f};

    if (wid < 7) {
#pragma unroll
        for (int s = 0; s < 4; ++s)
#pragma unroll
            for (int fj = 0; fj < 7; ++fj) {
                const int jr  = 16 * fj + t;
                const int off = jr * 128 + (((4 * s + g) ^ (jr & 7)) << 3);
                bf16x8 kh = *(const bf16x8*)&KTh[off];
                acc[fj] = __builtin_amdgcn_mfma_f32_16x16x32_bf16(qh[s], kh, acc[fj], 0, 0, 0);
            }

        // ---- softmax over j ----
        float mx[4], sm[4];
#pragma unroll
        for (int q = 0; q < 4; ++q) {
            mx[q] = acc[0][q];
#pragma unroll
            for (int fj = 1; fj < 7; ++fj) mx[q] = fmaxf(mx[q], acc[fj][q]);
#pragma unroll
            for (int off = 1; off < 16; off <<= 1) mx[q] = fmaxf(mx[q], __shfl_xor(mx[q], off));
            sm[q] = 0.f;
        }
#pragma unroll
        for (int fj = 0; fj < 7; ++fj)
#pragma unroll
            for (int q = 0; q < 4; ++q) {
                float e = __expf(acc[fj][q] - mx[q]);
                acc[fj][q] = e;
                sm[q] += e;
            }
#pragma unroll
        for (int q = 0; q < 4; ++q) {
#pragma unroll
            for (int off = 1; off < 16; off <<= 1) sm[q] += __shfl_xor(sm[q], off);
            sm[q] = 1.0f / sm[q];
        }
#pragma unroll
        for (int fj = 0; fj < 7; ++fj)
#pragma unroll
            for (int q = 0; q < 4; ++q) acc[fj][q] *= sm[q];
    }

    __syncthreads();   // all waves done reading KT before M overwrites it

    if (wid < 7) {
        // write M (bf16) into KT region, own rows (within-wave RAW on PV)
#pragma unroll
        for (int fj = 0; fj < 7; ++fj)
#pragma unroll
            for (int q = 0; q < 4; ++q) {
                const int i = 16 * wid + 4 * g + q;
                const int j = 16 * fj + t;
                const int col = (((j >> 3) ^ (i & 7)) << 3) | (j & 7);
                KTh[i * 128 + col] = (short)f2bf_rne(acc[fj][q]);
            }

        // ---- PV ----
        f32x4 zc[7];
#pragma unroll
        for (int fw = 0; fw < 7; ++fw) zc[fw] = (f32x4){0.f, 0.f, 0.f, 0.f};
#pragma unroll
        for (int s = 0; s < 4; ++s) {
            const int ir   = 16 * wid + t;
            bf16x8 mh = *(const bf16x8*)&KTh[ir * 128 + (((4 * s + g) ^ (ir & 7)) << 3)];
#pragma unroll
            for (int fw = 0; fw < 7; ++fw) {
                const int vr  = 16 * fw + t;
                bf16x8 bh = *(const bf16x8*)&VTh[vr * 128 + (((4 * s + g) ^ (vr & 7)) << 3)];
                zc[fw] = __builtin_amdgcn_mfma_f32_16x16x32_bf16(mh, bh, zc[fw], 0, 0, 0);
            }
        }

        float* Zp = Zg + (size_t)bc * HW;
#pragma unroll
        for (int fw = 0; fw < 7; ++fw)
#pragma unroll
            for (int q = 0; q < 4; ++q)
                Zp[(size_t)(16 * wid + 4 * g + q) * 112 + 16 * fw + t] = zc[fw][q];
    }
}

extern "C" void kernel_launch(void* const* d_in, const int* in_sizes, int n_in,
                              void* d_out, int out_size, void* d_ws, size_t ws_size,
                              hipStream_t stream) {
    const float* x  = (const float*)d_in[0];
    const float* y  = (const float*)d_in[1];
    const float* WQ = (const float*)d_in[2];
    const float* WK = (const float*)d_in[3];
    const float* WV = (const float*)d_in[4];
    const float* WZ = (const float*)d_in[5];
    float* out = (float*)d_out;

    const size_t n = (size_t)BB * CCH * HW;   // 25,690,112 elements

    // Workspace (2*n floats = 205.5 MB):
    //   Q -> d_out (consumed by attn, then d_out fully rewritten by final conv)
    //   K -> ws[0..n), V -> ws[n..2n); Z aliases K (per-block stage-then-write)
    float* Qb = out;
    float* Kb = (float*)d_ws;
    float* Vb = Kb + n;
    float* Zb = Kb;

    dim3 grid(98, 2, 8), blk(256);
    conv_mfma<<<grid, blk, 0, stream>>>(WQ, x, Qb, nullptr);
    conv_mfma<<<grid, blk, 0, stream>>>(WK, y, Kb, nullptr);
    conv_mfma<<<grid, blk, 0, stream>>>(WV, y, Vb, nullptr);
    attn_bf16<<<dim3(2048), 512, 0, stream>>>(Qb, Kb, Vb, Zb);
    conv_mfma<<<grid, blk, 0, stream>>>(WZ, Zb, out, x);
}